// Round 9
// baseline (496.175 us; speedup 1.0000x reference)
//
#include <hip/hip_runtime.h>

#define NN 100000
#define NE 800000
#define NRG 128       // dst ranges per relation
#define SPAN 784      // nodes per range (128*784 = 100352 >= NN)
#define CAP 8192      // capacity per (relation,range) bin; mean 6250, +24 sigma
#define NBIN (9 * NRG)

typedef _Float16 f16;
typedef __attribute__((ext_vector_type(4))) _Float16 f16x4;
typedef __attribute__((ext_vector_type(8))) _Float16 f16x8;
typedef __attribute__((ext_vector_type(4))) float f32x4;
typedef __attribute__((ext_vector_type(2))) float f32x2;

struct EPtrs { const int* s[9]; const int* d[9]; };

// ---------------- prep: combined weights ----------------
__global__ __launch_bounds__(256) void prep_weights(
    const float* __restrict__ W0n, const float* __restrict__ W0r, const float* __restrict__ b0,
    const float* __restrict__ W1n, const float* __restrict__ W1r, const float* __restrict__ b1,
    const float* __restrict__ P1,  const float* __restrict__ pb1,
    const float* __restrict__ W2n, const float* __restrict__ W2r, const float* __restrict__ b2,
    const float* __restrict__ P2,  const float* __restrict__ pb2,
    float* __restrict__ wc0, float* __restrict__ bc0,
    float* __restrict__ wc1, float* __restrict__ bc1,
    f16*   __restrict__ b2frag, float* __restrict__ bc2)
{
    int tid = threadIdx.x;
    for (int t = tid; t < 18 * 16; t += 256) {
        int row = t >> 4, col = t & 15;
        float v;
        if (row < 6)       v = W0n[row * 16 + col];
        else if (row < 12) v = W0n[96 + (row - 6) * 16 + col];
        else               v = W0r[(row - 12) * 16 + col] + W0r[96 + (row - 12) * 16 + col];
        wc0[t] = v;
    }
    for (int t = tid; t < 16; t += 256) bc0[t] = b0[t] + b0[16 + t];

    for (int t = tid; t < 48 * 32; t += 256) {
        int row = t >> 5, col = t & 31;
        float v;
        if (row < 16)      v = W1n[row * 32 + col];
        else if (row < 32) v = W1n[512 + (row - 16) * 32 + col];
        else { int rr = row - 32; v = W1r[rr * 32 + col] + W1r[512 + rr * 32 + col] + P1[rr * 32 + col]; }
        wc1[t] = v;
    }
    for (int t = tid; t < 32; t += 256) bc1[t] = b1[t] + b1[32 + t] + pb1[t];

    for (int t = tid; t < 256 * 64; t += 256) {
        int j = t & 7, lane = (t >> 3) & 63, ntk = t >> 9;
        int nt = ntk & 3, kt = ntk >> 2;
        int k = kt * 32 + (lane >> 4) * 8 + j;
        int n = nt * 16 + (lane & 15);
        float v;
        if (k < 224) v = W2n[k * 64 + n];
        else {
            int rr = k - 224;
            v = P2[rr * 64 + n];
            #pragma unroll
            for (int r = 0; r < 7; ++r) v += W2r[r * 2048 + rr * 64 + n];
        }
        b2frag[t] = (f16)v;
    }
    for (int t = tid; t < 64; t += 256) {
        float v = pb2[t];
        #pragma unroll
        for (int r = 0; r < 7; ++r) v += b2[r * 64 + t];
        bc2[t] = v;
    }
}

// ---------------- pass A: bucket edges by dst range, packed (dstLocal<<17)|src ----------------
__global__ __launch_bounds__(256) void passA(EPtrs ep, int* __restrict__ cursor,
                                             unsigned* __restrict__ binbuf)
{
    int r = blockIdx.y;
    int e0 = blockIdx.x * 4096;
    int cnt = min(4096, NE - e0);
    int tid = threadIdx.x;
    __shared__ int h[NRG];
    __shared__ int bs[NRG + 1];
    __shared__ int cl[NRG];
    __shared__ int gb[NRG];
    __shared__ int auxtot;
    __shared__ unsigned pk[4096];

    if (tid < NRG) h[tid] = 0;
    __syncthreads();

    const int* dp = ep.d[r];
    const int* sp = ep.s[r];
    unsigned wv[16];
    int rgk[16];
    #pragma unroll
    for (int k = 0; k < 16; ++k) {
        int e = e0 + k * 256 + tid;
        rgk[k] = -1;
        if (e < NE) {
            int d = dp[e];
            int sv = sp[e];
            int g = d / SPAN;
            int l = d - g * SPAN;
            wv[k] = ((unsigned)l << 17) | (unsigned)sv;
            rgk[k] = g;
            atomicAdd(&h[g], 1);
        }
    }
    __syncthreads();

    int vcnt = 0, incl = 0;
    if (tid < NRG) {
        vcnt = h[tid];
        incl = vcnt;
        int lane = tid & 63;
        #pragma unroll
        for (int ofs = 1; ofs < 64; ofs <<= 1) {
            int u = __shfl_up(incl, ofs, 64);
            if (lane >= ofs) incl += u;
        }
        if (tid == 63) auxtot = incl;
    }
    __syncthreads();
    if (tid < NRG) {
        int excl = incl - vcnt + ((tid >= 64) ? auxtot : 0);
        bs[tid] = excl;
        cl[tid] = excl;
        gb[tid] = (vcnt > 0) ? atomicAdd(&cursor[r * NRG + tid], vcnt) : 0;
        if (tid == NRG - 1) bs[NRG] = excl + vcnt;
    }
    __syncthreads();

    #pragma unroll
    for (int k = 0; k < 16; ++k) {
        if (rgk[k] >= 0) {
            int p = atomicAdd(&cl[rgk[k]], 1);
            pk[p] = wv[k];
        }
    }
    __syncthreads();

    for (int i = tid; i < cnt; i += 256) {
        int loB = 0, hiB = NRG;
        while (hiB - loB > 1) {
            int mid = (loB + hiB) >> 1;
            if (bs[mid] <= i) loB = mid; else hiB = mid;
        }
        int b = loB;
        int pos = gb[b] + (i - bs[b]);
        if (pos < CAP)
            binbuf[((size_t)(r * NRG + b)) * CAP + pos] = pk[i];
    }
}

// ---------------- pass B: per-bin counting sort; dense deg/off/eidx writes ----------------
__global__ __launch_bounds__(256) void passB(const unsigned* __restrict__ binbuf,
                                             const int* __restrict__ cursor,
                                             int* __restrict__ deg, int* __restrict__ off,
                                             int* __restrict__ eidx)
{
    int bin = blockIdx.x;
    int r = bin >> 7, rg = bin & (NRG - 1);
    int lo = rg * SPAN;
    int n_here = min(SPAN, NN - lo);
    int tid = threadIdx.x;
    __shared__ int h[SPAN];
    __shared__ int wsum[4];
    __shared__ int stage[CAP];

    int sz = min(cursor[bin], CAP);
    const unsigned* bp = binbuf + (size_t)bin * CAP;

    for (int i = tid; i < SPAN; i += 256) h[i] = 0;
    __syncthreads();
    for (int e = tid; e < sz; e += 256) atomicAdd(&h[bp[e] >> 17], 1);
    __syncthreads();

    int i0 = tid * 4;
    int dstash[4];
    int s = 0;
    #pragma unroll
    for (int k = 0; k < 4; ++k) {
        int i = i0 + k;
        int v = (i < SPAN) ? h[i] : 0;
        dstash[k] = v;
        s += v;
    }
    int lane = tid & 63, wid = tid >> 6;
    int incl = s;
    #pragma unroll
    for (int ofs = 1; ofs < 64; ofs <<= 1) {
        int u = __shfl_up(incl, ofs, 64);
        if (lane >= ofs) incl += u;
    }
    if (lane == 63) wsum[wid] = incl;
    __syncthreads();
    if (tid == 0) {
        int a = wsum[0], b = wsum[1], c = wsum[2];
        wsum[0] = 0; wsum[1] = a; wsum[2] = a + b; wsum[3] = a + b + c;
    }
    __syncthreads();
    int run = incl - s + wsum[wid];
    int base = bin * CAP;
    #pragma unroll
    for (int k = 0; k < 4; ++k) {
        int i = i0 + k;
        if (i < SPAN) {
            int v = dstash[k];
            h[i] = run;
            if (i < n_here) {
                deg[r * NN + lo + i] = v;
                off[r * NN + lo + i] = base + run + v;   // absolute row end
            }
            run += v;
        }
    }
    __syncthreads();

    for (int e = tid; e < sz; e += 256) {
        unsigned w = bp[e];
        int p = atomicAdd(&h[w >> 17], 1);
        stage[p] = (int)(w & 0x1FFFF);
    }
    __syncthreads();
    for (int i = tid; i < sz; i += 256) eidx[base + i] = stage[i];
}

// ---------------- layer 0 fused gather+transform: x(6) -> h0h(16 f16) ----------------
__global__ __launch_bounds__(256, 4) void t0f(const float* __restrict__ x,
                                              const int* __restrict__ deg, const int* __restrict__ off,
                                              const int* __restrict__ eidx,
                                              const float* __restrict__ wc0, const float* __restrict__ bc0,
                                              f16* __restrict__ h0h)
{
    __shared__ float sw[288 + 16];
    for (int t = threadIdx.x; t < 304; t += 256) sw[t] = (t < 288) ? wc0[t] : bc0[t - 288];
    __syncthreads();
    int n = blockIdx.x * 256 + threadIdx.x;
    if (n >= NN) return;
    float acc[16];
    #pragma unroll
    for (int j = 0; j < 16; ++j) acc[j] = sw[288 + j];
    float xv[6];
    {
        const float2* xp = reinterpret_cast<const float2*>(x + (size_t)n * 6);
        float2 a = xp[0], b = xp[1], c = xp[2];
        xv[0] = a.x; xv[1] = a.y; xv[2] = b.x; xv[3] = b.y; xv[4] = c.x; xv[5] = c.y;
    }
    #pragma unroll
    for (int r = 0; r < 2; ++r) {
        float m[6] = {0, 0, 0, 0, 0, 0};
        int e1 = off[r * NN + n];
        int e0 = e1 - deg[r * NN + n];
        int e = e0;
        for (; e + 2 <= e1; e += 2) {           // unroll-2: 6 independent loads in flight
            int sA = eidx[e], sB = eidx[e + 1];
            const float2* pA = reinterpret_cast<const float2*>(x + (size_t)sA * 6);
            const float2* pB = reinterpret_cast<const float2*>(x + (size_t)sB * 6);
            float2 a0 = pA[0], a1 = pA[1], a2 = pA[2];
            float2 b0 = pB[0], b1 = pB[1], b2 = pB[2];
            m[0] += a0.x + b0.x; m[1] += a0.y + b0.y;
            m[2] += a1.x + b1.x; m[3] += a1.y + b1.y;
            m[4] += a2.x + b2.x; m[5] += a2.y + b2.y;
        }
        if (e < e1) {
            int sA = eidx[e];
            const float2* pA = reinterpret_cast<const float2*>(x + (size_t)sA * 6);
            float2 a0 = pA[0], a1 = pA[1], a2 = pA[2];
            m[0] += a0.x; m[1] += a0.y; m[2] += a1.x; m[3] += a1.y; m[4] += a2.x; m[5] += a2.y;
        }
        #pragma unroll
        for (int k = 0; k < 6; ++k) {
            float s = m[k];
            #pragma unroll
            for (int j = 0; j < 16; ++j) acc[j] = fmaf(s, sw[(r * 6 + k) * 16 + j], acc[j]);
        }
    }
    #pragma unroll
    for (int k = 0; k < 6; ++k) {
        float s = xv[k];
        #pragma unroll
        for (int j = 0; j < 16; ++j) acc[j] = fmaf(s, sw[(12 + k) * 16 + j], acc[j]);
    }
    f16x8 o0, o1;
    #pragma unroll
    for (int j = 0; j < 8; ++j) { o0[j] = (f16)acc[j]; o1[j] = (f16)acc[8 + j]; }
    f16x8* op = reinterpret_cast<f16x8*>(h0h + (size_t)n * 16);
    op[0] = o0; op[1] = o1;
}

// ---------------- layer 1 fused: h0h(16) -> h1: f16 into cat slot 224 + fp8 e4m3 h1q ----------------
// __launch_bounds__(256,4): cap VGPR at ~128 -- round-8's unroll-2 pushed the
// allocator to 256 VGPR (occupancy 7.7%, latency-starved). k-split FMA halves
// keep fewer sw values hoisted at once.
__global__ __launch_bounds__(256, 4) void t1f(const f16* __restrict__ h0h,
                                              const int* __restrict__ deg, const int* __restrict__ off,
                                              const int* __restrict__ eidx,
                                              const float* __restrict__ wc1, const float* __restrict__ bc1,
                                              f16* __restrict__ m2cat, unsigned* __restrict__ h1q)
{
    __shared__ float sw[1536 + 32];
    for (int t = threadIdx.x; t < 1568; t += 256) sw[t] = (t < 1536) ? wc1[t] : bc1[t - 1536];
    __syncthreads();
    int n = blockIdx.x * 256 + threadIdx.x;
    if (n >= NN) return;
    float acc[32];
    #pragma unroll
    for (int j = 0; j < 32; ++j) acc[j] = sw[1536 + j];
    #pragma unroll
    for (int r = 0; r < 2; ++r) {
        float m[16];
        #pragma unroll
        for (int k = 0; k < 16; ++k) m[k] = 0.f;
        int e1 = off[r * NN + n];
        int e0 = e1 - deg[r * NN + n];
        int e = e0;
        for (; e + 2 <= e1; e += 2) {           // unroll-2: 4 table loads in flight
            int sA = eidx[e], sB = eidx[e + 1];
            const f16x8* pA = reinterpret_cast<const f16x8*>(h0h + (size_t)sA * 16);
            const f16x8* pB = reinterpret_cast<const f16x8*>(h0h + (size_t)sB * 16);
            f16x8 a0 = pA[0], a1 = pA[1];
            f16x8 b0 = pB[0], b1 = pB[1];
            #pragma unroll
            for (int k = 0; k < 8; ++k) {
                m[k]     += (float)a0[k] + (float)b0[k];
                m[8 + k] += (float)a1[k] + (float)b1[k];
            }
        }
        if (e < e1) {
            int sA = eidx[e];
            const f16x8* pA = reinterpret_cast<const f16x8*>(h0h + (size_t)sA * 16);
            f16x8 a0 = pA[0], a1 = pA[1];
            #pragma unroll
            for (int k = 0; k < 8; ++k) { m[k] += (float)a0[k]; m[8 + k] += (float)a1[k]; }
        }
        // k-split FMA: two halves to limit concurrently hoisted sw values
        #pragma unroll
        for (int k = 0; k < 8; ++k) {
            float s = m[k];
            #pragma unroll
            for (int j = 0; j < 32; ++j) acc[j] = fmaf(s, sw[(r * 16 + k) * 32 + j], acc[j]);
        }
        #pragma unroll
        for (int k = 8; k < 16; ++k) {
            float s = m[k];
            #pragma unroll
            for (int j = 0; j < 32; ++j) acc[j] = fmaf(s, sw[(r * 16 + k) * 32 + j], acc[j]);
        }
    }
    {
        const f16x8* hp = reinterpret_cast<const f16x8*>(h0h + (size_t)n * 16);
        f16x8 a = hp[0], b = hp[1];
        #pragma unroll
        for (int k = 0; k < 8; ++k) {
            float s0 = (float)a[k], s1 = (float)b[k];
            #pragma unroll
            for (int j = 0; j < 32; ++j)
                acc[j] = fmaf(s0, sw[(32 + k) * 32 + j], fmaf(s1, sw[(40 + k) * 32 + j], acc[j]));
        }
    }
    #pragma unroll
    for (int j = 0; j < 32; ++j) acc[j] = fmaxf(acc[j], 0.f);

    f16x8* op = reinterpret_cast<f16x8*>(m2cat + (size_t)n * 256 + 224);
    #pragma unroll
    for (int q = 0; q < 4; ++q) {
        f16x8 o;
        #pragma unroll
        for (int j = 0; j < 8; ++j) o[j] = (f16)acc[q * 8 + j];
        op[q] = o;
    }
    unsigned qw[8];
    #pragma unroll
    for (int q = 0; q < 8; ++q) {
        int w = __builtin_amdgcn_cvt_pk_fp8_f32(acc[q * 4 + 0], acc[q * 4 + 1], 0, false);
        w = __builtin_amdgcn_cvt_pk_fp8_f32(acc[q * 4 + 2], acc[q * 4 + 3], w, true);
        qw[q] = (unsigned)w;
    }
    uint4* qp = reinterpret_cast<uint4*>(h1q + (size_t)n * 8);
    qp[0] = make_uint4(qw[0], qw[1], qw[2], qw[3]);
    qp[1] = make_uint4(qw[4], qw[5], qw[6], qw[7]);
}

// ---------------- layer 2 gather: relation-fused, fp8 table, 4-deep pipelined ----------------
__global__ __launch_bounds__(256) void g2(const int* __restrict__ deg, const int* __restrict__ off,
                                          const int* __restrict__ eidx, const unsigned* __restrict__ h1q,
                                          f16* __restrict__ m2cat)
{
    int t = blockIdx.x * 256 + threadIdx.x;     // 3125*256 == NN*8 exactly
    int node = t >> 3, l = t & 7;
    f16* outp = m2cat + (size_t)node * 256 + l * 4;

    int dd[7], oo[7];                            // hoisted broadcast loads, one wait
    #pragma unroll
    for (int r = 0; r < 7; ++r) {
        dd[r] = deg[(r + 2) * NN + node];
        oo[r] = off[(r + 2) * NN + node];
    }

    #pragma unroll 1
    for (int r = 0; r < 7; ++r) {
        int e1 = oo[r];
        int e0 = e1 - dd[r];
        float a0 = 0.f, a1 = 0.f, a2 = 0.f, a3 = 0.f;
        int e = e0;
        for (; e + 4 <= e1; e += 4) {            // 4 eidx then 4 h1q loads in flight
            int sA = eidx[e], sB = eidx[e + 1], sC = eidx[e + 2], sD = eidx[e + 3];
            unsigned wA = h1q[(size_t)sA * 8 + l];
            unsigned wB = h1q[(size_t)sB * 8 + l];
            unsigned wC = h1q[(size_t)sC * 8 + l];
            unsigned wD = h1q[(size_t)sD * 8 + l];
            f32x2 lA = __builtin_amdgcn_cvt_pk_f32_fp8(wA, false), hA = __builtin_amdgcn_cvt_pk_f32_fp8(wA, true);
            f32x2 lB = __builtin_amdgcn_cvt_pk_f32_fp8(wB, false), hB = __builtin_amdgcn_cvt_pk_f32_fp8(wB, true);
            f32x2 lC = __builtin_amdgcn_cvt_pk_f32_fp8(wC, false), hC = __builtin_amdgcn_cvt_pk_f32_fp8(wC, true);
            f32x2 lD = __builtin_amdgcn_cvt_pk_f32_fp8(wD, false), hD = __builtin_amdgcn_cvt_pk_f32_fp8(wD, true);
            a0 += lA[0] + lB[0] + lC[0] + lD[0];
            a1 += lA[1] + lB[1] + lC[1] + lD[1];
            a2 += hA[0] + hB[0] + hC[0] + hD[0];
            a3 += hA[1] + hB[1] + hC[1] + hD[1];
        }
        for (; e < e1; ++e) {
            unsigned w = h1q[(size_t)eidx[e] * 8 + l];
            f32x2 lo = __builtin_amdgcn_cvt_pk_f32_fp8(w, false);
            f32x2 hi = __builtin_amdgcn_cvt_pk_f32_fp8(w, true);
            a0 += lo[0]; a1 += lo[1]; a2 += hi[0]; a3 += hi[1];
        }
        float sc = (r == 2 || r == 3 || r == 6) ? (1.0f / (float)max(dd[r], 1)) : 1.0f;
        f16x4 o;
        o[0] = (f16)(a0 * sc); o[1] = (f16)(a1 * sc); o[2] = (f16)(a2 * sc); o[3] = (f16)(a3 * sc);
        *reinterpret_cast<f16x4*>(outp + r * 32) = o;
    }
}

// ---------------- layer 2 transform: MFMA GEMM [100000x256] x [256x64] + bias, relu ----------------
__global__ __launch_bounds__(256) void t2(const f16* __restrict__ m2cat, const f16* __restrict__ b2frag,
                                          const float* __restrict__ bc2, float* __restrict__ out)
{
    int lane = threadIdx.x & 63;
    int gw = blockIdx.x * 4 + (threadIdx.x >> 6);
    int NW = gridDim.x * 4;
    int quad = lane >> 4, col0 = lane & 15;

    f16x8 bf[32];
    #pragma unroll
    for (int i = 0; i < 32; ++i)
        bf[i] = *reinterpret_cast<const f16x8*>(b2frag + ((size_t)i * 64 + lane) * 8);
    float bcv[4];
    #pragma unroll
    for (int nt = 0; nt < 4; ++nt) bcv[nt] = bc2[nt * 16 + col0];

    for (int mt = gw; mt < NN / 16; mt += NW) {
        const f16* arow = m2cat + ((size_t)(mt * 16 + col0)) * 256 + quad * 8;
        f16x8 af[8];
        #pragma unroll
        for (int kt = 0; kt < 8; ++kt)
            af[kt] = *reinterpret_cast<const f16x8*>(arow + kt * 32);
        f32x4 acc[4];
        #pragma unroll
        for (int nt = 0; nt < 4; ++nt) acc[nt] = (f32x4){0.f, 0.f, 0.f, 0.f};
        #pragma unroll
        for (int kt = 0; kt < 8; ++kt) {
            #pragma unroll
            for (int nt = 0; nt < 4; ++nt)
                acc[nt] = __builtin_amdgcn_mfma_f32_16x16x32_f16(af[kt], bf[kt * 4 + nt], acc[nt], 0, 0, 0);
        }
        #pragma unroll
        for (int nt = 0; nt < 4; ++nt) {
            #pragma unroll
            for (int i = 0; i < 4; ++i) {
                int row = mt * 16 + quad * 4 + i;
                out[(size_t)row * 64 + nt * 16 + col0] = fmaxf(acc[nt][i] + bcv[nt], 0.f);
            }
        }
    }
}

// ---------------- launch ----------------
extern "C" void kernel_launch(void* const* d_in, const int* in_sizes, int n_in,
                              void* d_out, int out_size, void* d_ws, size_t ws_size,
                              hipStream_t stream)
{
    const float* x = (const float*)d_in[0];
    EPtrs ep;
    for (int i = 0; i < 9; ++i) { const int* p = (const int*)d_in[1 + i]; ep.s[i] = p; ep.d[i] = p + NE; }
    const float* W0n = (const float*)d_in[10]; const float* W0r = (const float*)d_in[11];
    const float* b0  = (const float*)d_in[12];
    const float* W1n = (const float*)d_in[13]; const float* W1r = (const float*)d_in[14];
    const float* b1  = (const float*)d_in[15];
    const float* P1  = (const float*)d_in[16]; const float* pb1 = (const float*)d_in[17];
    const float* W2n = (const float*)d_in[18]; const float* W2r = (const float*)d_in[19];
    const float* b2  = (const float*)d_in[20];
    const float* P2  = (const float*)d_in[21]; const float* pb2 = (const float*)d_in[22];
    float* out = (float*)d_out;
    char* ws = (char*)d_ws;

    size_t off_b = 0;
    auto alloc = [&](size_t b) { size_t o = off_b; off_b += (b + 255) & ~(size_t)255; return o; };
    size_t o_wc0 = alloc(288 * 4);   size_t o_bc0 = alloc(16 * 4);
    size_t o_wc1 = alloc(1536 * 4);  size_t o_bc1 = alloc(32 * 4);
    size_t o_b2f = alloc(16384 * 2); size_t o_bc2 = alloc(64 * 4);
    size_t o_h0h = alloc((size_t)NN * 16 * 2);
    size_t o_h1q = alloc((size_t)NN * 32);             // fp8 e4m3 gather table (3.2 MB, fits 4 MB L2)
    size_t o_cat = alloc((size_t)NN * 256 * 2);        // binbuf aliases this (dead before t1f)
    size_t o_deg = alloc((size_t)9 * NN * 4);
    size_t o_off = alloc((size_t)9 * NN * 4);
    size_t o_eid = alloc((size_t)NBIN * CAP * 4);
    size_t o_cur = alloc((size_t)NBIN * 4);
    (void)ws_size;  // ~99 MB total; round-1 full path proved >= ~128 MB available

    float* wc0 = (float*)(ws + o_wc0); float* bc0 = (float*)(ws + o_bc0);
    float* wc1 = (float*)(ws + o_wc1); float* bc1 = (float*)(ws + o_bc1);
    f16*   b2f = (f16*)(ws + o_b2f);   float* bc2 = (float*)(ws + o_bc2);
    f16*   h0h = (f16*)(ws + o_h0h);
    unsigned* h1q = (unsigned*)(ws + o_h1q);
    f16*   cat = (f16*)(ws + o_cat);
    unsigned* binbuf = (unsigned*)(ws + o_cat);
    int*   deg = (int*)(ws + o_deg);
    int*   offp = (int*)(ws + o_off);
    int*   eid = (int*)(ws + o_eid);
    int*   cur = (int*)(ws + o_cur);

    dim3 B(256);
    prep_weights<<<1, B, 0, stream>>>(W0n, W0r, b0, W1n, W1r, b1, P1, pb1,
                                      W2n, W2r, b2, P2, pb2,
                                      wc0, bc0, wc1, bc1, b2f, bc2);
    hipMemsetAsync(cur, 0, (size_t)NBIN * 4, stream);
    passA<<<dim3((NE + 4095) / 4096, 9), B, 0, stream>>>(ep, cur, binbuf);
    passB<<<NBIN, B, 0, stream>>>(binbuf, cur, deg, offp, eid);

    t0f<<<(NN + 255) / 256, B, 0, stream>>>(x, deg, offp, eid, wc0, bc0, h0h);
    t1f<<<(NN + 255) / 256, B, 0, stream>>>(h0h, deg, offp, eid, wc1, bc1, cat, h1q);
    g2<<<NN * 8 / 256, B, 0, stream>>>(deg, offp, eid, h1q, cat);
    t2<<<512, B, 0, stream>>>(cat, b2f, bc2, out);
}

// Round 10
// 422.753 us; speedup vs baseline: 1.1737x; 1.1737x over previous
//
#include <hip/hip_runtime.h>

#define NN 100000
#define NE 800000
#define NRG 128       // dst ranges per relation
#define SPAN 784      // nodes per range (128*784 = 100352 >= NN)
#define CAP 8192      // capacity per (relation,range) bin; mean 6250, +24 sigma
#define NBIN (9 * NRG)

typedef _Float16 f16;
typedef __attribute__((ext_vector_type(4))) _Float16 f16x4;
typedef __attribute__((ext_vector_type(8))) _Float16 f16x8;
typedef __attribute__((ext_vector_type(4))) float f32x4;
typedef __attribute__((ext_vector_type(2))) float f32x2;

struct EPtrs { const int* s[9]; const int* d[9]; };

// ---------------- prep: combined weights ----------------
__global__ __launch_bounds__(256) void prep_weights(
    const float* __restrict__ W0n, const float* __restrict__ W0r, const float* __restrict__ b0,
    const float* __restrict__ W1n, const float* __restrict__ W1r, const float* __restrict__ b1,
    const float* __restrict__ P1,  const float* __restrict__ pb1,
    const float* __restrict__ W2n, const float* __restrict__ W2r, const float* __restrict__ b2,
    const float* __restrict__ P2,  const float* __restrict__ pb2,
    float* __restrict__ wc0, float* __restrict__ bc0,
    float* __restrict__ wc1, float* __restrict__ bc1,
    f16*   __restrict__ b2frag, float* __restrict__ bc2)
{
    int tid = threadIdx.x;
    for (int t = tid; t < 18 * 16; t += 256) {
        int row = t >> 4, col = t & 15;
        float v;
        if (row < 6)       v = W0n[row * 16 + col];
        else if (row < 12) v = W0n[96 + (row - 6) * 16 + col];
        else               v = W0r[(row - 12) * 16 + col] + W0r[96 + (row - 12) * 16 + col];
        wc0[t] = v;
    }
    for (int t = tid; t < 16; t += 256) bc0[t] = b0[t] + b0[16 + t];

    for (int t = tid; t < 48 * 32; t += 256) {
        int row = t >> 5, col = t & 31;
        float v;
        if (row < 16)      v = W1n[row * 32 + col];
        else if (row < 32) v = W1n[512 + (row - 16) * 32 + col];
        else { int rr = row - 32; v = W1r[rr * 32 + col] + W1r[512 + rr * 32 + col] + P1[rr * 32 + col]; }
        wc1[t] = v;
    }
    for (int t = tid; t < 32; t += 256) bc1[t] = b1[t] + b1[32 + t] + pb1[t];

    for (int t = tid; t < 256 * 64; t += 256) {
        int j = t & 7, lane = (t >> 3) & 63, ntk = t >> 9;
        int nt = ntk & 3, kt = ntk >> 2;
        int k = kt * 32 + (lane >> 4) * 8 + j;
        int n = nt * 16 + (lane & 15);
        float v;
        if (k < 224) v = W2n[k * 64 + n];
        else {
            int rr = k - 224;
            v = P2[rr * 64 + n];
            #pragma unroll
            for (int r = 0; r < 7; ++r) v += W2r[r * 2048 + rr * 64 + n];
        }
        b2frag[t] = (f16)v;
    }
    for (int t = tid; t < 64; t += 256) {
        float v = pb2[t];
        #pragma unroll
        for (int r = 0; r < 7; ++r) v += b2[r * 64 + t];
        bc2[t] = v;
    }
}

// ---------------- pass A: bucket edges by dst range, packed (dstLocal<<17)|src ----------------
__global__ __launch_bounds__(256) void passA(EPtrs ep, int* __restrict__ cursor,
                                             unsigned* __restrict__ binbuf)
{
    int r = blockIdx.y;
    int e0 = blockIdx.x * 4096;
    int cnt = min(4096, NE - e0);
    int tid = threadIdx.x;
    __shared__ int h[NRG];
    __shared__ int bs[NRG + 1];
    __shared__ int cl[NRG];
    __shared__ int gb[NRG];
    __shared__ int auxtot;
    __shared__ unsigned pk[4096];

    if (tid < NRG) h[tid] = 0;
    __syncthreads();

    const int* dp = ep.d[r];
    const int* sp = ep.s[r];
    unsigned wv[16];
    int rgk[16];
    #pragma unroll
    for (int k = 0; k < 16; ++k) {
        int e = e0 + k * 256 + tid;
        rgk[k] = -1;
        if (e < NE) {
            int d = dp[e];
            int sv = sp[e];
            int g = d / SPAN;
            int l = d - g * SPAN;
            wv[k] = ((unsigned)l << 17) | (unsigned)sv;
            rgk[k] = g;
            atomicAdd(&h[g], 1);
        }
    }
    __syncthreads();

    int vcnt = 0, incl = 0;
    if (tid < NRG) {
        vcnt = h[tid];
        incl = vcnt;
        int lane = tid & 63;
        #pragma unroll
        for (int ofs = 1; ofs < 64; ofs <<= 1) {
            int u = __shfl_up(incl, ofs, 64);
            if (lane >= ofs) incl += u;
        }
        if (tid == 63) auxtot = incl;
    }
    __syncthreads();
    if (tid < NRG) {
        int excl = incl - vcnt + ((tid >= 64) ? auxtot : 0);
        bs[tid] = excl;
        cl[tid] = excl;
        gb[tid] = (vcnt > 0) ? atomicAdd(&cursor[r * NRG + tid], vcnt) : 0;
        if (tid == NRG - 1) bs[NRG] = excl + vcnt;
    }
    __syncthreads();

    #pragma unroll
    for (int k = 0; k < 16; ++k) {
        if (rgk[k] >= 0) {
            int p = atomicAdd(&cl[rgk[k]], 1);
            pk[p] = wv[k];
        }
    }
    __syncthreads();

    for (int i = tid; i < cnt; i += 256) {
        int loB = 0, hiB = NRG;
        while (hiB - loB > 1) {
            int mid = (loB + hiB) >> 1;
            if (bs[mid] <= i) loB = mid; else hiB = mid;
        }
        int b = loB;
        int pos = gb[b] + (i - bs[b]);
        if (pos < CAP)
            binbuf[((size_t)(r * NRG + b)) * CAP + pos] = pk[i];
    }
}

// ---------------- pass B: per-bin counting sort; dense deg/off/eidx writes ----------------
__global__ __launch_bounds__(256) void passB(const unsigned* __restrict__ binbuf,
                                             const int* __restrict__ cursor,
                                             int* __restrict__ deg, int* __restrict__ off,
                                             int* __restrict__ eidx)
{
    int bin = blockIdx.x;
    int r = bin >> 7, rg = bin & (NRG - 1);
    int lo = rg * SPAN;
    int n_here = min(SPAN, NN - lo);
    int tid = threadIdx.x;
    __shared__ int h[SPAN];
    __shared__ int wsum[4];
    __shared__ int stage[CAP];

    int sz = min(cursor[bin], CAP);
    const unsigned* bp = binbuf + (size_t)bin * CAP;

    for (int i = tid; i < SPAN; i += 256) h[i] = 0;
    __syncthreads();
    for (int e = tid; e < sz; e += 256) atomicAdd(&h[bp[e] >> 17], 1);
    __syncthreads();

    int i0 = tid * 4;
    int dstash[4];
    int s = 0;
    #pragma unroll
    for (int k = 0; k < 4; ++k) {
        int i = i0 + k;
        int v = (i < SPAN) ? h[i] : 0;
        dstash[k] = v;
        s += v;
    }
    int lane = tid & 63, wid = tid >> 6;
    int incl = s;
    #pragma unroll
    for (int ofs = 1; ofs < 64; ofs <<= 1) {
        int u = __shfl_up(incl, ofs, 64);
        if (lane >= ofs) incl += u;
    }
    if (lane == 63) wsum[wid] = incl;
    __syncthreads();
    if (tid == 0) {
        int a = wsum[0], b = wsum[1], c = wsum[2];
        wsum[0] = 0; wsum[1] = a; wsum[2] = a + b; wsum[3] = a + b + c;
    }
    __syncthreads();
    int run = incl - s + wsum[wid];
    int base = bin * CAP;
    #pragma unroll
    for (int k = 0; k < 4; ++k) {
        int i = i0 + k;
        if (i < SPAN) {
            int v = dstash[k];
            h[i] = run;
            if (i < n_here) {
                deg[r * NN + lo + i] = v;
                off[r * NN + lo + i] = base + run + v;   // absolute row end
            }
            run += v;
        }
    }
    __syncthreads();

    for (int e = tid; e < sz; e += 256) {
        unsigned w = bp[e];
        int p = atomicAdd(&h[w >> 17], 1);
        stage[p] = (int)(w & 0x1FFFF);
    }
    __syncthreads();
    for (int i = tid; i < sz; i += 256) eidx[base + i] = stage[i];
}

// ---------------- layer 0 fused gather+transform: x(6) -> h0h(16 f16) ----------------
// (256,2): empirical arg->VGPR map on this compiler is 512/(2*arg); arg 2 -> 128 cap.
__global__ __launch_bounds__(256, 2) void t0f(const float* __restrict__ x,
                                              const int* __restrict__ deg, const int* __restrict__ off,
                                              const int* __restrict__ eidx,
                                              const float* __restrict__ wc0, const float* __restrict__ bc0,
                                              f16* __restrict__ h0h)
{
    __shared__ float sw[288 + 16];
    for (int t = threadIdx.x; t < 304; t += 256) sw[t] = (t < 288) ? wc0[t] : bc0[t - 288];
    __syncthreads();
    int n = blockIdx.x * 256 + threadIdx.x;
    if (n >= NN) return;
    float acc[16];
    #pragma unroll
    for (int j = 0; j < 16; ++j) acc[j] = sw[288 + j];
    float xv[6];
    {
        const float2* xp = reinterpret_cast<const float2*>(x + (size_t)n * 6);
        float2 a = xp[0], b = xp[1], c = xp[2];
        xv[0] = a.x; xv[1] = a.y; xv[2] = b.x; xv[3] = b.y; xv[4] = c.x; xv[5] = c.y;
    }
    #pragma unroll
    for (int r = 0; r < 2; ++r) {
        float m[6] = {0, 0, 0, 0, 0, 0};
        int e1 = off[r * NN + n];
        int e0 = e1 - deg[r * NN + n];
        int e = e0;
        for (; e + 2 <= e1; e += 2) {           // unroll-2: 6 independent loads in flight
            int sA = eidx[e], sB = eidx[e + 1];
            const float2* pA = reinterpret_cast<const float2*>(x + (size_t)sA * 6);
            const float2* pB = reinterpret_cast<const float2*>(x + (size_t)sB * 6);
            float2 a0 = pA[0], a1 = pA[1], a2 = pA[2];
            float2 b0 = pB[0], b1 = pB[1], b2 = pB[2];
            m[0] += a0.x + b0.x; m[1] += a0.y + b0.y;
            m[2] += a1.x + b1.x; m[3] += a1.y + b1.y;
            m[4] += a2.x + b2.x; m[5] += a2.y + b2.y;
        }
        if (e < e1) {
            int sA = eidx[e];
            const float2* pA = reinterpret_cast<const float2*>(x + (size_t)sA * 6);
            float2 a0 = pA[0], a1 = pA[1], a2 = pA[2];
            m[0] += a0.x; m[1] += a0.y; m[2] += a1.x; m[3] += a1.y; m[4] += a2.x; m[5] += a2.y;
        }
        #pragma unroll
        for (int k = 0; k < 6; ++k) {
            float s = m[k];
            #pragma unroll
            for (int j = 0; j < 16; ++j) acc[j] = fmaf(s, sw[(r * 6 + k) * 16 + j], acc[j]);
        }
    }
    #pragma unroll
    for (int k = 0; k < 6; ++k) {
        float s = xv[k];
        #pragma unroll
        for (int j = 0; j < 16; ++j) acc[j] = fmaf(s, sw[(12 + k) * 16 + j], acc[j]);
    }
    f16x8 o0, o1;
    #pragma unroll
    for (int j = 0; j < 8; ++j) { o0[j] = (f16)acc[j]; o1[j] = (f16)acc[8 + j]; }
    f16x8* op = reinterpret_cast<f16x8*>(h0h + (size_t)n * 16);
    op[0] = o0; op[1] = o1;
}

// ---------------- layer 1 fused: h0h(16) -> h1: f16 into cat slot 224 + fp8 e4m3 h1q ----------------
// (256,2) -> ~128 VGPR cap: above the ~80-reg live set (no spill), 2x round-8 occupancy.
__global__ __launch_bounds__(256, 2) void t1f(const f16* __restrict__ h0h,
                                              const int* __restrict__ deg, const int* __restrict__ off,
                                              const int* __restrict__ eidx,
                                              const float* __restrict__ wc1, const float* __restrict__ bc1,
                                              f16* __restrict__ m2cat, unsigned* __restrict__ h1q)
{
    __shared__ float sw[1536 + 32];
    for (int t = threadIdx.x; t < 1568; t += 256) sw[t] = (t < 1536) ? wc1[t] : bc1[t - 1536];
    __syncthreads();
    int n = blockIdx.x * 256 + threadIdx.x;
    if (n >= NN) return;
    float acc[32];
    #pragma unroll
    for (int j = 0; j < 32; ++j) acc[j] = sw[1536 + j];
    #pragma unroll
    for (int r = 0; r < 2; ++r) {
        float m[16];
        #pragma unroll
        for (int k = 0; k < 16; ++k) m[k] = 0.f;
        int e1 = off[r * NN + n];
        int e0 = e1 - deg[r * NN + n];
        int e = e0;
        for (; e + 2 <= e1; e += 2) {           // unroll-2: 4 table loads in flight
            int sA = eidx[e], sB = eidx[e + 1];
            const f16x8* pA = reinterpret_cast<const f16x8*>(h0h + (size_t)sA * 16);
            const f16x8* pB = reinterpret_cast<const f16x8*>(h0h + (size_t)sB * 16);
            f16x8 a0 = pA[0], a1 = pA[1];
            f16x8 b0 = pB[0], b1 = pB[1];
            #pragma unroll
            for (int k = 0; k < 8; ++k) {
                m[k]     += (float)a0[k] + (float)b0[k];
                m[8 + k] += (float)a1[k] + (float)b1[k];
            }
        }
        if (e < e1) {
            int sA = eidx[e];
            const f16x8* pA = reinterpret_cast<const f16x8*>(h0h + (size_t)sA * 16);
            f16x8 a0 = pA[0], a1 = pA[1];
            #pragma unroll
            for (int k = 0; k < 8; ++k) { m[k] += (float)a0[k]; m[8 + k] += (float)a1[k]; }
        }
        // k-split FMA: two halves to limit concurrently hoisted sw values
        #pragma unroll
        for (int k = 0; k < 8; ++k) {
            float s = m[k];
            #pragma unroll
            for (int j = 0; j < 32; ++j) acc[j] = fmaf(s, sw[(r * 16 + k) * 32 + j], acc[j]);
        }
        #pragma unroll
        for (int k = 8; k < 16; ++k) {
            float s = m[k];
            #pragma unroll
            for (int j = 0; j < 32; ++j) acc[j] = fmaf(s, sw[(r * 16 + k) * 32 + j], acc[j]);
        }
    }
    {
        const f16x8* hp = reinterpret_cast<const f16x8*>(h0h + (size_t)n * 16);
        f16x8 a = hp[0], b = hp[1];
        #pragma unroll
        for (int k = 0; k < 8; ++k) {
            float s0 = (float)a[k], s1 = (float)b[k];
            #pragma unroll
            for (int j = 0; j < 32; ++j)
                acc[j] = fmaf(s0, sw[(32 + k) * 32 + j], fmaf(s1, sw[(40 + k) * 32 + j], acc[j]));
        }
    }
    #pragma unroll
    for (int j = 0; j < 32; ++j) acc[j] = fmaxf(acc[j], 0.f);

    f16x8* op = reinterpret_cast<f16x8*>(m2cat + (size_t)n * 256 + 224);
    #pragma unroll
    for (int q = 0; q < 4; ++q) {
        f16x8 o;
        #pragma unroll
        for (int j = 0; j < 8; ++j) o[j] = (f16)acc[q * 8 + j];
        op[q] = o;
    }
    unsigned qw[8];
    #pragma unroll
    for (int q = 0; q < 8; ++q) {
        int w = __builtin_amdgcn_cvt_pk_fp8_f32(acc[q * 4 + 0], acc[q * 4 + 1], 0, false);
        w = __builtin_amdgcn_cvt_pk_fp8_f32(acc[q * 4 + 2], acc[q * 4 + 3], w, true);
        qw[q] = (unsigned)w;
    }
    uint4* qp = reinterpret_cast<uint4*>(h1q + (size_t)n * 8);
    qp[0] = make_uint4(qw[0], qw[1], qw[2], qw[3]);
    qp[1] = make_uint4(qw[4], qw[5], qw[6], qw[7]);
}

// ---------------- layer 2 gather: relation-fused, fp8 table, 4-deep pipelined ----------------
__global__ __launch_bounds__(256) void g2(const int* __restrict__ deg, const int* __restrict__ off,
                                          const int* __restrict__ eidx, const unsigned* __restrict__ h1q,
                                          f16* __restrict__ m2cat)
{
    int t = blockIdx.x * 256 + threadIdx.x;     // 3125*256 == NN*8 exactly
    int node = t >> 3, l = t & 7;
    f16* outp = m2cat + (size_t)node * 256 + l * 4;

    int dd[7], oo[7];                            // hoisted broadcast loads, one wait
    #pragma unroll
    for (int r = 0; r < 7; ++r) {
        dd[r] = deg[(r + 2) * NN + node];
        oo[r] = off[(r + 2) * NN + node];
    }

    #pragma unroll 1
    for (int r = 0; r < 7; ++r) {
        int e1 = oo[r];
        int e0 = e1 - dd[r];
        float a0 = 0.f, a1 = 0.f, a2 = 0.f, a3 = 0.f;
        int e = e0;
        for (; e + 4 <= e1; e += 4) {            // 4 eidx then 4 h1q loads in flight
            int sA = eidx[e], sB = eidx[e + 1], sC = eidx[e + 2], sD = eidx[e + 3];
            unsigned wA = h1q[(size_t)sA * 8 + l];
            unsigned wB = h1q[(size_t)sB * 8 + l];
            unsigned wC = h1q[(size_t)sC * 8 + l];
            unsigned wD = h1q[(size_t)sD * 8 + l];
            f32x2 lA = __builtin_amdgcn_cvt_pk_f32_fp8(wA, false), hA = __builtin_amdgcn_cvt_pk_f32_fp8(wA, true);
            f32x2 lB = __builtin_amdgcn_cvt_pk_f32_fp8(wB, false), hB = __builtin_amdgcn_cvt_pk_f32_fp8(wB, true);
            f32x2 lC = __builtin_amdgcn_cvt_pk_f32_fp8(wC, false), hC = __builtin_amdgcn_cvt_pk_f32_fp8(wC, true);
            f32x2 lD = __builtin_amdgcn_cvt_pk_f32_fp8(wD, false), hD = __builtin_amdgcn_cvt_pk_f32_fp8(wD, true);
            a0 += lA[0] + lB[0] + lC[0] + lD[0];
            a1 += lA[1] + lB[1] + lC[1] + lD[1];
            a2 += hA[0] + hB[0] + hC[0] + hD[0];
            a3 += hA[1] + hB[1] + hC[1] + hD[1];
        }
        for (; e < e1; ++e) {
            unsigned w = h1q[(size_t)eidx[e] * 8 + l];
            f32x2 lo = __builtin_amdgcn_cvt_pk_f32_fp8(w, false);
            f32x2 hi = __builtin_amdgcn_cvt_pk_f32_fp8(w, true);
            a0 += lo[0]; a1 += lo[1]; a2 += hi[0]; a3 += hi[1];
        }
        float sc = (r == 2 || r == 3 || r == 6) ? (1.0f / (float)max(dd[r], 1)) : 1.0f;
        f16x4 o;
        o[0] = (f16)(a0 * sc); o[1] = (f16)(a1 * sc); o[2] = (f16)(a2 * sc); o[3] = (f16)(a3 * sc);
        *reinterpret_cast<f16x4*>(outp + r * 32) = o;
    }
}

// ---------------- layer 2 transform: MFMA GEMM [100000x256] x [256x64] + bias, relu ----------------
__global__ __launch_bounds__(256) void t2(const f16* __restrict__ m2cat, const f16* __restrict__ b2frag,
                                          const float* __restrict__ bc2, float* __restrict__ out)
{
    int lane = threadIdx.x & 63;
    int gw = blockIdx.x * 4 + (threadIdx.x >> 6);
    int NW = gridDim.x * 4;
    int quad = lane >> 4, col0 = lane & 15;

    f16x8 bf[32];
    #pragma unroll
    for (int i = 0; i < 32; ++i)
        bf[i] = *reinterpret_cast<const f16x8*>(b2frag + ((size_t)i * 64 + lane) * 8);
    float bcv[4];
    #pragma unroll
    for (int nt = 0; nt < 4; ++nt) bcv[nt] = bc2[nt * 16 + col0];

    for (int mt = gw; mt < NN / 16; mt += NW) {
        const f16* arow = m2cat + ((size_t)(mt * 16 + col0)) * 256 + quad * 8;
        f16x8 af[8];
        #pragma unroll
        for (int kt = 0; kt < 8; ++kt)
            af[kt] = *reinterpret_cast<const f16x8*>(arow + kt * 32);
        f32x4 acc[4];
        #pragma unroll
        for (int nt = 0; nt < 4; ++nt) acc[nt] = (f32x4){0.f, 0.f, 0.f, 0.f};
        #pragma unroll
        for (int kt = 0; kt < 8; ++kt) {
            #pragma unroll
            for (int nt = 0; nt < 4; ++nt)
                acc[nt] = __builtin_amdgcn_mfma_f32_16x16x32_f16(af[kt], bf[kt * 4 + nt], acc[nt], 0, 0, 0);
        }
        #pragma unroll
        for (int nt = 0; nt < 4; ++nt) {
            #pragma unroll
            for (int i = 0; i < 4; ++i) {
                int row = mt * 16 + quad * 4 + i;
                out[(size_t)row * 64 + nt * 16 + col0] = fmaxf(acc[nt][i] + bcv[nt], 0.f);
            }
        }
    }
}

// ---------------- launch ----------------
extern "C" void kernel_launch(void* const* d_in, const int* in_sizes, int n_in,
                              void* d_out, int out_size, void* d_ws, size_t ws_size,
                              hipStream_t stream)
{
    const float* x = (const float*)d_in[0];
    EPtrs ep;
    for (int i = 0; i < 9; ++i) { const int* p = (const int*)d_in[1 + i]; ep.s[i] = p; ep.d[i] = p + NE; }
    const float* W0n = (const float*)d_in[10]; const float* W0r = (const float*)d_in[11];
    const float* b0  = (const float*)d_in[12];
    const float* W1n = (const float*)d_in[13]; const float* W1r = (const float*)d_in[14];
    const float* b1  = (const float*)d_in[15];
    const float* P1  = (const float*)d_in[16]; const float* pb1 = (const float*)d_in[17];
    const float* W2n = (const float*)d_in[18]; const float* W2r = (const float*)d_in[19];
    const float* b2  = (const float*)d_in[20];
    const float* P2  = (const float*)d_in[21]; const float* pb2 = (const float*)d_in[22];
    float* out = (float*)d_out;
    char* ws = (char*)d_ws;

    size_t off_b = 0;
    auto alloc = [&](size_t b) { size_t o = off_b; off_b += (b + 255) & ~(size_t)255; return o; };
    size_t o_wc0 = alloc(288 * 4);   size_t o_bc0 = alloc(16 * 4);
    size_t o_wc1 = alloc(1536 * 4);  size_t o_bc1 = alloc(32 * 4);
    size_t o_b2f = alloc(16384 * 2); size_t o_bc2 = alloc(64 * 4);
    size_t o_h0h = alloc((size_t)NN * 16 * 2);
    size_t o_h1q = alloc((size_t)NN * 32);             // fp8 e4m3 gather table (3.2 MB, fits 4 MB L2)
    size_t o_cat = alloc((size_t)NN * 256 * 2);        // binbuf aliases this (dead before t1f)
    size_t o_deg = alloc((size_t)9 * NN * 4);
    size_t o_off = alloc((size_t)9 * NN * 4);
    size_t o_eid = alloc((size_t)NBIN * CAP * 4);
    size_t o_cur = alloc((size_t)NBIN * 4);
    (void)ws_size;  // ~99 MB total; round-1 full path proved >= ~128 MB available

    float* wc0 = (float*)(ws + o_wc0); float* bc0 = (float*)(ws + o_bc0);
    float* wc1 = (float*)(ws + o_wc1); float* bc1 = (float*)(ws + o_bc1);
    f16*   b2f = (f16*)(ws + o_b2f);   float* bc2 = (float*)(ws + o_bc2);
    f16*   h0h = (f16*)(ws + o_h0h);
    unsigned* h1q = (unsigned*)(ws + o_h1q);
    f16*   cat = (f16*)(ws + o_cat);
    unsigned* binbuf = (unsigned*)(ws + o_cat);
    int*   deg = (int*)(ws + o_deg);
    int*   offp = (int*)(ws + o_off);
    int*   eid = (int*)(ws + o_eid);
    int*   cur = (int*)(ws + o_cur);

    dim3 B(256);
    prep_weights<<<1, B, 0, stream>>>(W0n, W0r, b0, W1n, W1r, b1, P1, pb1,
                                      W2n, W2r, b2, P2, pb2,
                                      wc0, bc0, wc1, bc1, b2f, bc2);
    hipMemsetAsync(cur, 0, (size_t)NBIN * 4, stream);
    passA<<<dim3((NE + 4095) / 4096, 9), B, 0, stream>>>(ep, cur, binbuf);
    passB<<<NBIN, B, 0, stream>>>(binbuf, cur, deg, offp, eid);

    t0f<<<(NN + 255) / 256, B, 0, stream>>>(x, deg, offp, eid, wc0, bc0, h0h);
    t1f<<<(NN + 255) / 256, B, 0, stream>>>(h0h, deg, offp, eid, wc1, bc1, cat, h1q);
    g2<<<NN * 8 / 256, B, 0, stream>>>(deg, offp, eid, h1q, cat);
    t2<<<512, B, 0, stream>>>(cat, b2f, bc2, out);
}

// Round 11
// 346.430 us; speedup vs baseline: 1.4323x; 1.2203x over previous
//
#include <hip/hip_runtime.h>

#define NN 100000
#define NE 800000
#define NRG 128       // dst ranges per relation
#define SPAN 784      // nodes per range (128*784 = 100352 >= NN)
#define CAP 8192      // capacity per (relation,range) bin; mean 6250, +24 sigma
#define NBIN (9 * NRG)

typedef _Float16 f16;
typedef __attribute__((ext_vector_type(4))) _Float16 f16x4;
typedef __attribute__((ext_vector_type(8))) _Float16 f16x8;
typedef __attribute__((ext_vector_type(4))) float f32x4;
typedef __attribute__((ext_vector_type(2))) float f32x2;

struct EPtrs { const int* s[9]; const int* d[9]; };

// ---------------- prep: combined weights ----------------
__global__ __launch_bounds__(256) void prep_weights(
    const float* __restrict__ W0n, const float* __restrict__ W0r, const float* __restrict__ b0,
    const float* __restrict__ W1n, const float* __restrict__ W1r, const float* __restrict__ b1,
    const float* __restrict__ P1,  const float* __restrict__ pb1,
    const float* __restrict__ W2n, const float* __restrict__ W2r, const float* __restrict__ b2,
    const float* __restrict__ P2,  const float* __restrict__ pb2,
    float* __restrict__ wc0, float* __restrict__ bc0,
    float* __restrict__ wc1, float* __restrict__ bc1,
    f16*   __restrict__ b2frag, float* __restrict__ bc2)
{
    int tid = threadIdx.x;
    for (int t = tid; t < 18 * 16; t += 256) {
        int row = t >> 4, col = t & 15;
        float v;
        if (row < 6)       v = W0n[row * 16 + col];
        else if (row < 12) v = W0n[96 + (row - 6) * 16 + col];
        else               v = W0r[(row - 12) * 16 + col] + W0r[96 + (row - 12) * 16 + col];
        wc0[t] = v;
    }
    for (int t = tid; t < 16; t += 256) bc0[t] = b0[t] + b0[16 + t];

    for (int t = tid; t < 48 * 32; t += 256) {
        int row = t >> 5, col = t & 31;
        float v;
        if (row < 16)      v = W1n[row * 32 + col];
        else if (row < 32) v = W1n[512 + (row - 16) * 32 + col];
        else { int rr = row - 32; v = W1r[rr * 32 + col] + W1r[512 + rr * 32 + col] + P1[rr * 32 + col]; }
        wc1[t] = v;
    }
    for (int t = tid; t < 32; t += 256) bc1[t] = b1[t] + b1[32 + t] + pb1[t];

    for (int t = tid; t < 256 * 64; t += 256) {
        int j = t & 7, lane = (t >> 3) & 63, ntk = t >> 9;
        int nt = ntk & 3, kt = ntk >> 2;
        int k = kt * 32 + (lane >> 4) * 8 + j;
        int n = nt * 16 + (lane & 15);
        float v;
        if (k < 224) v = W2n[k * 64 + n];
        else {
            int rr = k - 224;
            v = P2[rr * 64 + n];
            #pragma unroll
            for (int r = 0; r < 7; ++r) v += W2r[r * 2048 + rr * 64 + n];
        }
        b2frag[t] = (f16)v;
    }
    for (int t = tid; t < 64; t += 256) {
        float v = pb2[t];
        #pragma unroll
        for (int r = 0; r < 7; ++r) v += b2[r * 64 + t];
        bc2[t] = v;
    }
}

// ---------------- pass A: bucket edges by dst range, packed (dstLocal<<17)|src ----------------
__global__ __launch_bounds__(256) void passA(EPtrs ep, int* __restrict__ cursor,
                                             unsigned* __restrict__ binbuf)
{
    int r = blockIdx.y;
    int e0 = blockIdx.x * 4096;
    int cnt = min(4096, NE - e0);
    int tid = threadIdx.x;
    __shared__ int h[NRG];
    __shared__ int bs[NRG + 1];
    __shared__ int cl[NRG];
    __shared__ int gb[NRG];
    __shared__ int auxtot;
    __shared__ unsigned pk[4096];

    if (tid < NRG) h[tid] = 0;
    __syncthreads();

    const int* dp = ep.d[r];
    const int* sp = ep.s[r];
    unsigned wv[16];
    int rgk[16];
    #pragma unroll
    for (int k = 0; k < 16; ++k) {
        int e = e0 + k * 256 + tid;
        rgk[k] = -1;
        if (e < NE) {
            int d = dp[e];
            int sv = sp[e];
            int g = d / SPAN;
            int l = d - g * SPAN;
            wv[k] = ((unsigned)l << 17) | (unsigned)sv;
            rgk[k] = g;
            atomicAdd(&h[g], 1);
        }
    }
    __syncthreads();

    int vcnt = 0, incl = 0;
    if (tid < NRG) {
        vcnt = h[tid];
        incl = vcnt;
        int lane = tid & 63;
        #pragma unroll
        for (int ofs = 1; ofs < 64; ofs <<= 1) {
            int u = __shfl_up(incl, ofs, 64);
            if (lane >= ofs) incl += u;
        }
        if (tid == 63) auxtot = incl;
    }
    __syncthreads();
    if (tid < NRG) {
        int excl = incl - vcnt + ((tid >= 64) ? auxtot : 0);
        bs[tid] = excl;
        cl[tid] = excl;
        gb[tid] = (vcnt > 0) ? atomicAdd(&cursor[r * NRG + tid], vcnt) : 0;
        if (tid == NRG - 1) bs[NRG] = excl + vcnt;
    }
    __syncthreads();

    #pragma unroll
    for (int k = 0; k < 16; ++k) {
        if (rgk[k] >= 0) {
            int p = atomicAdd(&cl[rgk[k]], 1);
            pk[p] = wv[k];
        }
    }
    __syncthreads();

    for (int i = tid; i < cnt; i += 256) {
        int loB = 0, hiB = NRG;
        while (hiB - loB > 1) {
            int mid = (loB + hiB) >> 1;
            if (bs[mid] <= i) loB = mid; else hiB = mid;
        }
        int b = loB;
        int pos = gb[b] + (i - bs[b]);
        if (pos < CAP)
            binbuf[((size_t)(r * NRG + b)) * CAP + pos] = pk[i];
    }
}

// ---------------- pass B: per-bin counting sort; dense deg/off/eidx writes ----------------
__global__ __launch_bounds__(256) void passB(const unsigned* __restrict__ binbuf,
                                             const int* __restrict__ cursor,
                                             int* __restrict__ deg, int* __restrict__ off,
                                             int* __restrict__ eidx)
{
    int bin = blockIdx.x;
    int r = bin >> 7, rg = bin & (NRG - 1);
    int lo = rg * SPAN;
    int n_here = min(SPAN, NN - lo);
    int tid = threadIdx.x;
    __shared__ int h[SPAN];
    __shared__ int wsum[4];
    __shared__ int stage[CAP];

    int sz = min(cursor[bin], CAP);
    const unsigned* bp = binbuf + (size_t)bin * CAP;

    for (int i = tid; i < SPAN; i += 256) h[i] = 0;
    __syncthreads();
    for (int e = tid; e < sz; e += 256) atomicAdd(&h[bp[e] >> 17], 1);
    __syncthreads();

    int i0 = tid * 4;
    int dstash[4];
    int s = 0;
    #pragma unroll
    for (int k = 0; k < 4; ++k) {
        int i = i0 + k;
        int v = (i < SPAN) ? h[i] : 0;
        dstash[k] = v;
        s += v;
    }
    int lane = tid & 63, wid = tid >> 6;
    int incl = s;
    #pragma unroll
    for (int ofs = 1; ofs < 64; ofs <<= 1) {
        int u = __shfl_up(incl, ofs, 64);
        if (lane >= ofs) incl += u;
    }
    if (lane == 63) wsum[wid] = incl;
    __syncthreads();
    if (tid == 0) {
        int a = wsum[0], b = wsum[1], c = wsum[2];
        wsum[0] = 0; wsum[1] = a; wsum[2] = a + b; wsum[3] = a + b + c;
    }
    __syncthreads();
    int run = incl - s + wsum[wid];
    int base = bin * CAP;
    #pragma unroll
    for (int k = 0; k < 4; ++k) {
        int i = i0 + k;
        if (i < SPAN) {
            int v = dstash[k];
            h[i] = run;
            if (i < n_here) {
                deg[r * NN + lo + i] = v;
                off[r * NN + lo + i] = base + run + v;   // absolute row end
            }
            run += v;
        }
    }
    __syncthreads();

    for (int e = tid; e < sz; e += 256) {
        unsigned w = bp[e];
        int p = atomicAdd(&h[w >> 17], 1);
        stage[p] = (int)(w & 0x1FFFF);
    }
    __syncthreads();
    for (int i = tid; i < sz; i += 256) eidx[base + i] = stage[i];
}

// ---------------- layer 0 fused gather+transform: x(6) -> h0h(16 f16) ----------------
__global__ __launch_bounds__(256, 2) void t0f(const float* __restrict__ x,
                                              const int* __restrict__ deg, const int* __restrict__ off,
                                              const int* __restrict__ eidx,
                                              const float* __restrict__ wc0, const float* __restrict__ bc0,
                                              f16* __restrict__ h0h)
{
    __shared__ float sw[288 + 16];
    for (int t = threadIdx.x; t < 304; t += 256) sw[t] = (t < 288) ? wc0[t] : bc0[t - 288];
    __syncthreads();
    int n = blockIdx.x * 256 + threadIdx.x;
    if (n >= NN) return;
    float acc[16];
    #pragma unroll
    for (int j = 0; j < 16; ++j) acc[j] = sw[288 + j];
    float xv[6];
    {
        const float2* xp = reinterpret_cast<const float2*>(x + (size_t)n * 6);
        float2 a = xp[0], b = xp[1], c = xp[2];
        xv[0] = a.x; xv[1] = a.y; xv[2] = b.x; xv[3] = b.y; xv[4] = c.x; xv[5] = c.y;
    }
    #pragma unroll
    for (int r = 0; r < 2; ++r) {
        float m[6] = {0, 0, 0, 0, 0, 0};
        int e1 = off[r * NN + n];
        int e0 = e1 - deg[r * NN + n];
        int e = e0;
        for (; e + 2 <= e1; e += 2) {
            int sA = eidx[e], sB = eidx[e + 1];
            const float2* pA = reinterpret_cast<const float2*>(x + (size_t)sA * 6);
            const float2* pB = reinterpret_cast<const float2*>(x + (size_t)sB * 6);
            float2 a0 = pA[0], a1 = pA[1], a2 = pA[2];
            float2 b0 = pB[0], b1 = pB[1], b2 = pB[2];
            m[0] += a0.x + b0.x; m[1] += a0.y + b0.y;
            m[2] += a1.x + b1.x; m[3] += a1.y + b1.y;
            m[4] += a2.x + b2.x; m[5] += a2.y + b2.y;
        }
        if (e < e1) {
            int sA = eidx[e];
            const float2* pA = reinterpret_cast<const float2*>(x + (size_t)sA * 6);
            float2 a0 = pA[0], a1 = pA[1], a2 = pA[2];
            m[0] += a0.x; m[1] += a0.y; m[2] += a1.x; m[3] += a1.y; m[4] += a2.x; m[5] += a2.y;
        }
        #pragma unroll
        for (int k = 0; k < 6; ++k) {
            float s = m[k];
            #pragma unroll
            for (int j = 0; j < 16; ++j) acc[j] = fmaf(s, sw[(r * 6 + k) * 16 + j], acc[j]);
        }
    }
    #pragma unroll
    for (int k = 0; k < 6; ++k) {
        float s = xv[k];
        #pragma unroll
        for (int j = 0; j < 16; ++j) acc[j] = fmaf(s, sw[(12 + k) * 16 + j], acc[j]);
    }
    f16x8 o0, o1;
    #pragma unroll
    for (int j = 0; j < 8; ++j) { o0[j] = (f16)acc[j]; o1[j] = (f16)acc[8 + j]; }
    f16x8* op = reinterpret_cast<f16x8*>(h0h + (size_t)n * 16);
    op[0] = o0; op[1] = o1;
}

// ---------------- layer 1 gather (g2-style): msum[n][r*16+dim] = sum of h0h over edges ----------------
// thread = (node, l in 0..3); lane l covers dims 4l..4l+3 (8 B f16x4 loads; h0h = 3.2 MB, L2-resident)
__global__ __launch_bounds__(256) void g1(const int* __restrict__ deg, const int* __restrict__ off,
                                          const int* __restrict__ eidx, const f16* __restrict__ h0h,
                                          f16* __restrict__ msum)
{
    int t = blockIdx.x * 256 + threadIdx.x;
    int node = t >> 2, l = t & 3;
    if (node >= NN) return;
    int dd[2], oo[2];
    #pragma unroll
    for (int r = 0; r < 2; ++r) { dd[r] = deg[r * NN + node]; oo[r] = off[r * NN + node]; }
    #pragma unroll 1
    for (int r = 0; r < 2; ++r) {
        int e1 = oo[r];
        int e0 = e1 - dd[r];
        float a0 = 0.f, a1 = 0.f, a2 = 0.f, a3 = 0.f;
        int e = e0;
        for (; e + 4 <= e1; e += 4) {          // 4 eidx then 4 table loads in flight
            int sA = eidx[e], sB = eidx[e + 1], sC = eidx[e + 2], sD = eidx[e + 3];
            f16x4 vA = *reinterpret_cast<const f16x4*>(h0h + (size_t)sA * 16 + l * 4);
            f16x4 vB = *reinterpret_cast<const f16x4*>(h0h + (size_t)sB * 16 + l * 4);
            f16x4 vC = *reinterpret_cast<const f16x4*>(h0h + (size_t)sC * 16 + l * 4);
            f16x4 vD = *reinterpret_cast<const f16x4*>(h0h + (size_t)sD * 16 + l * 4);
            a0 += (float)vA[0] + (float)vB[0] + (float)vC[0] + (float)vD[0];
            a1 += (float)vA[1] + (float)vB[1] + (float)vC[1] + (float)vD[1];
            a2 += (float)vA[2] + (float)vB[2] + (float)vC[2] + (float)vD[2];
            a3 += (float)vA[3] + (float)vB[3] + (float)vC[3] + (float)vD[3];
        }
        for (; e < e1; ++e) {
            f16x4 v = *reinterpret_cast<const f16x4*>(h0h + (size_t)eidx[e] * 16 + l * 4);
            a0 += (float)v[0]; a1 += (float)v[1]; a2 += (float)v[2]; a3 += (float)v[3];
        }
        f16x4 o;
        o[0] = (f16)a0; o[1] = (f16)a1; o[2] = (f16)a2; o[3] = (f16)a3;
        *reinterpret_cast<f16x4*>(msum + (size_t)node * 32 + r * 16 + l * 4) = o;
    }
}

// ---------------- layer 1 transform (no gather): msum+h0h -> cat slot 224 + h1q ----------------
__global__ __launch_bounds__(256) void t1t(const f16* __restrict__ h0h, const f16* __restrict__ msum,
                                           const float* __restrict__ wc1, const float* __restrict__ bc1,
                                           f16* __restrict__ m2cat, unsigned* __restrict__ h1q)
{
    __shared__ float sw[1536 + 32];
    for (int t = threadIdx.x; t < 1568; t += 256) sw[t] = (t < 1536) ? wc1[t] : bc1[t - 1536];
    __syncthreads();
    int n = blockIdx.x * 256 + threadIdx.x;
    if (n >= NN) return;
    float acc[32];
    #pragma unroll
    for (int j = 0; j < 32; ++j) acc[j] = sw[1536 + j];
    {
        const f16x8* mp = reinterpret_cast<const f16x8*>(msum + (size_t)n * 32);
        f16x8 m0 = mp[0], m1 = mp[1], m2 = mp[2], m3 = mp[3];  // rows 0-7, 8-15, 16-23, 24-31
        #pragma unroll
        for (int k = 0; k < 8; ++k) {
            float s0 = (float)m0[k], s1 = (float)m1[k];
            float s2 = (float)m2[k], s3 = (float)m3[k];
            #pragma unroll
            for (int j = 0; j < 32; ++j)
                acc[j] += s0 * sw[k * 32 + j] + s1 * sw[(8 + k) * 32 + j]
                        + s2 * sw[(16 + k) * 32 + j] + s3 * sw[(24 + k) * 32 + j];
        }
    }
    {
        const f16x8* hp = reinterpret_cast<const f16x8*>(h0h + (size_t)n * 16);
        f16x8 a = hp[0], b = hp[1];
        #pragma unroll
        for (int k = 0; k < 8; ++k) {
            float s0 = (float)a[k], s1 = (float)b[k];
            #pragma unroll
            for (int j = 0; j < 32; ++j)
                acc[j] = fmaf(s0, sw[(32 + k) * 32 + j], fmaf(s1, sw[(40 + k) * 32 + j], acc[j]));
        }
    }
    #pragma unroll
    for (int j = 0; j < 32; ++j) acc[j] = fmaxf(acc[j], 0.f);

    f16x8* op = reinterpret_cast<f16x8*>(m2cat + (size_t)n * 256 + 224);
    #pragma unroll
    for (int q = 0; q < 4; ++q) {
        f16x8 o;
        #pragma unroll
        for (int j = 0; j < 8; ++j) o[j] = (f16)acc[q * 8 + j];
        op[q] = o;
    }
    unsigned qw[8];
    #pragma unroll
    for (int q = 0; q < 8; ++q) {
        int w = __builtin_amdgcn_cvt_pk_fp8_f32(acc[q * 4 + 0], acc[q * 4 + 1], 0, false);
        w = __builtin_amdgcn_cvt_pk_fp8_f32(acc[q * 4 + 2], acc[q * 4 + 3], w, true);
        qw[q] = (unsigned)w;
    }
    uint4* qp = reinterpret_cast<uint4*>(h1q + (size_t)n * 8);
    qp[0] = make_uint4(qw[0], qw[1], qw[2], qw[3]);
    qp[1] = make_uint4(qw[4], qw[5], qw[6], qw[7]);
}

// ---------------- layer 2 gather: relation-fused, fp8 table, 4-deep pipelined ----------------
__global__ __launch_bounds__(256) void g2(const int* __restrict__ deg, const int* __restrict__ off,
                                          const int* __restrict__ eidx, const unsigned* __restrict__ h1q,
                                          f16* __restrict__ m2cat)
{
    int t = blockIdx.x * 256 + threadIdx.x;     // 3125*256 == NN*8 exactly
    int node = t >> 3, l = t & 7;
    f16* outp = m2cat + (size_t)node * 256 + l * 4;

    int dd[7], oo[7];
    #pragma unroll
    for (int r = 0; r < 7; ++r) {
        dd[r] = deg[(r + 2) * NN + node];
        oo[r] = off[(r + 2) * NN + node];
    }

    #pragma unroll 1
    for (int r = 0; r < 7; ++r) {
        int e1 = oo[r];
        int e0 = e1 - dd[r];
        float a0 = 0.f, a1 = 0.f, a2 = 0.f, a3 = 0.f;
        int e = e0;
        for (; e + 4 <= e1; e += 4) {
            int sA = eidx[e], sB = eidx[e + 1], sC = eidx[e + 2], sD = eidx[e + 3];
            unsigned wA = h1q[(size_t)sA * 8 + l];
            unsigned wB = h1q[(size_t)sB * 8 + l];
            unsigned wC = h1q[(size_t)sC * 8 + l];
            unsigned wD = h1q[(size_t)sD * 8 + l];
            f32x2 lA = __builtin_amdgcn_cvt_pk_f32_fp8(wA, false), hA = __builtin_amdgcn_cvt_pk_f32_fp8(wA, true);
            f32x2 lB = __builtin_amdgcn_cvt_pk_f32_fp8(wB, false), hB = __builtin_amdgcn_cvt_pk_f32_fp8(wB, true);
            f32x2 lC = __builtin_amdgcn_cvt_pk_f32_fp8(wC, false), hC = __builtin_amdgcn_cvt_pk_f32_fp8(wC, true);
            f32x2 lD = __builtin_amdgcn_cvt_pk_f32_fp8(wD, false), hD = __builtin_amdgcn_cvt_pk_f32_fp8(wD, true);
            a0 += lA[0] + lB[0] + lC[0] + lD[0];
            a1 += lA[1] + lB[1] + lC[1] + lD[1];
            a2 += hA[0] + hB[0] + hC[0] + hD[0];
            a3 += hA[1] + hB[1] + hC[1] + hD[1];
        }
        for (; e < e1; ++e) {
            unsigned w = h1q[(size_t)eidx[e] * 8 + l];
            f32x2 lo = __builtin_amdgcn_cvt_pk_f32_fp8(w, false);
            f32x2 hi = __builtin_amdgcn_cvt_pk_f32_fp8(w, true);
            a0 += lo[0]; a1 += lo[1]; a2 += hi[0]; a3 += hi[1];
        }
        float sc = (r == 2 || r == 3 || r == 6) ? (1.0f / (float)max(dd[r], 1)) : 1.0f;
        f16x4 o;
        o[0] = (f16)(a0 * sc); o[1] = (f16)(a1 * sc); o[2] = (f16)(a2 * sc); o[3] = (f16)(a3 * sc);
        *reinterpret_cast<f16x4*>(outp + r * 32) = o;
    }
}

// ---------------- layer 2 transform: MFMA GEMM [100000x256] x [256x64] + bias, relu ----------------
__global__ __launch_bounds__(256) void t2(const f16* __restrict__ m2cat, const f16* __restrict__ b2frag,
                                          const float* __restrict__ bc2, float* __restrict__ out)
{
    int lane = threadIdx.x & 63;
    int gw = blockIdx.x * 4 + (threadIdx.x >> 6);
    int NW = gridDim.x * 4;
    int quad = lane >> 4, col0 = lane & 15;

    f16x8 bf[32];
    #pragma unroll
    for (int i = 0; i < 32; ++i)
        bf[i] = *reinterpret_cast<const f16x8*>(b2frag + ((size_t)i * 64 + lane) * 8);
    float bcv[4];
    #pragma unroll
    for (int nt = 0; nt < 4; ++nt) bcv[nt] = bc2[nt * 16 + col0];

    for (int mt = gw; mt < NN / 16; mt += NW) {
        const f16* arow = m2cat + ((size_t)(mt * 16 + col0)) * 256 + quad * 8;
        f16x8 af[8];
        #pragma unroll
        for (int kt = 0; kt < 8; ++kt)
            af[kt] = *reinterpret_cast<const f16x8*>(arow + kt * 32);
        f32x4 acc[4];
        #pragma unroll
        for (int nt = 0; nt < 4; ++nt) acc[nt] = (f32x4){0.f, 0.f, 0.f, 0.f};
        #pragma unroll
        for (int kt = 0; kt < 8; ++kt) {
            #pragma unroll
            for (int nt = 0; nt < 4; ++nt)
                acc[nt] = __builtin_amdgcn_mfma_f32_16x16x32_f16(af[kt], bf[kt * 4 + nt], acc[nt], 0, 0, 0);
        }
        #pragma unroll
        for (int nt = 0; nt < 4; ++nt) {
            #pragma unroll
            for (int i = 0; i < 4; ++i) {
                int row = mt * 16 + quad * 4 + i;
                out[(size_t)row * 64 + nt * 16 + col0] = fmaxf(acc[nt][i] + bcv[nt], 0.f);
            }
        }
    }
}

// ---------------- launch ----------------
extern "C" void kernel_launch(void* const* d_in, const int* in_sizes, int n_in,
                              void* d_out, int out_size, void* d_ws, size_t ws_size,
                              hipStream_t stream)
{
    const float* x = (const float*)d_in[0];
    EPtrs ep;
    for (int i = 0; i < 9; ++i) { const int* p = (const int*)d_in[1 + i]; ep.s[i] = p; ep.d[i] = p + NE; }
    const float* W0n = (const float*)d_in[10]; const float* W0r = (const float*)d_in[11];
    const float* b0  = (const float*)d_in[12];
    const float* W1n = (const float*)d_in[13]; const float* W1r = (const float*)d_in[14];
    const float* b1  = (const float*)d_in[15];
    const float* P1  = (const float*)d_in[16]; const float* pb1 = (const float*)d_in[17];
    const float* W2n = (const float*)d_in[18]; const float* W2r = (const float*)d_in[19];
    const float* b2  = (const float*)d_in[20];
    const float* P2  = (const float*)d_in[21]; const float* pb2 = (const float*)d_in[22];
    float* out = (float*)d_out;
    char* ws = (char*)d_ws;

    size_t off_b = 0;
    auto alloc = [&](size_t b) { size_t o = off_b; off_b += (b + 255) & ~(size_t)255; return o; };
    size_t o_wc0 = alloc(288 * 4);   size_t o_bc0 = alloc(16 * 4);
    size_t o_wc1 = alloc(1536 * 4);  size_t o_bc1 = alloc(32 * 4);
    size_t o_b2f = alloc(16384 * 2); size_t o_bc2 = alloc(64 * 4);
    size_t o_h0h = alloc((size_t)NN * 16 * 2);
    size_t o_h1q = alloc((size_t)NN * 32);             // fp8 e4m3 gather table (3.2 MB, fits 4 MB L2)
    size_t o_msum = alloc((size_t)NN * 32 * 2);        // layer-1 gathered sums (6.4 MB)
    size_t o_cat = alloc((size_t)NN * 256 * 2);        // binbuf aliases this (dead before t1t)
    size_t o_deg = alloc((size_t)9 * NN * 4);
    size_t o_off = alloc((size_t)9 * NN * 4);
    size_t o_eid = alloc((size_t)NBIN * CAP * 4);
    size_t o_cur = alloc((size_t)NBIN * 4);
    (void)ws_size;  // ~105 MB total; round-1 full path proved >= ~128 MB available

    float* wc0 = (float*)(ws + o_wc0); float* bc0 = (float*)(ws + o_bc0);
    float* wc1 = (float*)(ws + o_wc1); float* bc1 = (float*)(ws + o_bc1);
    f16*   b2f = (f16*)(ws + o_b2f);   float* bc2 = (float*)(ws + o_bc2);
    f16*   h0h = (f16*)(ws + o_h0h);
    unsigned* h1q = (unsigned*)(ws + o_h1q);
    f16*   msum = (f16*)(ws + o_msum);
    f16*   cat = (f16*)(ws + o_cat);
    unsigned* binbuf = (unsigned*)(ws + o_cat);
    int*   deg = (int*)(ws + o_deg);
    int*   offp = (int*)(ws + o_off);
    int*   eid = (int*)(ws + o_eid);
    int*   cur = (int*)(ws + o_cur);

    dim3 B(256);
    prep_weights<<<1, B, 0, stream>>>(W0n, W0r, b0, W1n, W1r, b1, P1, pb1,
                                      W2n, W2r, b2, P2, pb2,
                                      wc0, bc0, wc1, bc1, b2f, bc2);
    hipMemsetAsync(cur, 0, (size_t)NBIN * 4, stream);
    passA<<<dim3((NE + 4095) / 4096, 9), B, 0, stream>>>(ep, cur, binbuf);
    passB<<<NBIN, B, 0, stream>>>(binbuf, cur, deg, offp, eid);

    t0f<<<(NN + 255) / 256, B, 0, stream>>>(x, deg, offp, eid, wc0, bc0, h0h);
    g1<<<(NN * 4 + 255) / 256, B, 0, stream>>>(deg, offp, eid, h0h, msum);
    t1t<<<(NN + 255) / 256, B, 0, stream>>>(h0h, msum, wc1, bc1, cat, h1q);
    g2<<<NN * 8 / 256, B, 0, stream>>>(deg, offp, eid, h1q, cat);
    t2<<<512, B, 0, stream>>>(cat, b2f, bc2, out);
}